// Round 4
// baseline (2244.974 us; speedup 1.0000x reference)
//
#include <hip/hip_runtime.h>

#define NU 200000
#define NI 100000
#define TOTR (NU + NI)   // merged dest rows: users 0..NU-1, items NU..NU+NI-1
#define NBK 586          // ceil(TOTR/512) row-buckets of 512 rows
#define EPB 8192         // edges per block in build kernels (32/thread)

// Embedding buffers are TYPE-MAJOR: [K=4][TOTR][64 bf16] = 4 x 38.4 MB pools.
// SpMM runs 2 passes per layer (types {0,1} then {2,3}); per pass the live
// gather pool is 77 MB (30% of L3) so Infinity Cache can hold it.

struct Bld {
  const int* rows[6]; const int* cols[6]; const float* vals[6];
  int base[6]; int coff[6];
  int eoff[7];  // exclusive prefix of edge counts over the 6 lists
};

// ---------------- bf16 helpers ----------------

__device__ __forceinline__ unsigned bfr(float f) {  // fp32 -> bf16 bits, RTNE
  unsigned u = __float_as_uint(f);
  return (u + 0x7FFFu + ((u >> 16) & 1u)) >> 16;
}
__device__ __forceinline__ float blo(unsigned p) { return __uint_as_float(p << 16); }
__device__ __forceinline__ float bhi(unsigned p) { return __uint_as_float(p & 0xFFFF0000u); }

__device__ __forceinline__ int list_of(const Bld& b, int g) {
  int l = 0;
#pragma unroll
  for (int k = 0; k < 5; ++k) l += (g >= b.eoff[k + 1]) ? 1 : 0;
  return l;
}

// ---------------- bucketed CSR build ----------------

// Pass 1: bucket histogram (LDS-aggregated; reads rows only)
__global__ __launch_bounds__(256) void bhist_k(Bld b, int* __restrict__ bcount, int totE) {
  __shared__ int cnt[NBK];
  int t = threadIdx.x;
  for (int i = t; i < NBK; i += 256) cnt[i] = 0;
  __syncthreads();
  int g0 = blockIdx.x * EPB;
  int gend = min(g0 + EPB, totE);
  for (int g = g0 + t; g < gend; g += 256) {
    int l = list_of(b, g);
    int i = g - b.eoff[l];
    int drow = b.base[l] + b.rows[l][i];
    atomicAdd(&cnt[drow >> 9], 1);
  }
  __syncthreads();
  for (int i = t; i < NBK; i += 256) if (cnt[i]) atomicAdd(&bcount[i], cnt[i]);
}

// Pass 2: exclusive scan of 586 bucket counts -> bbase, bcursor; offs[TOTR]=totE
__global__ __launch_bounds__(256) void bscan_k(const int* __restrict__ bcount,
    int* __restrict__ bbase, int* __restrict__ bcursor, int* __restrict__ offs) {
  __shared__ int s_run;
  __shared__ int wsum[4];
  int t = threadIdx.x, lane = t & 63, wv = t >> 6;
  if (t == 0) s_run = 0;
  __syncthreads();
  for (int base = 0; base < NBK; base += 256) {
    int v = (base + t < NBK) ? bcount[base + t] : 0;
    int sc = v;
#pragma unroll
    for (int o = 1; o < 64; o <<= 1) { int x = __shfl_up(sc, o, 64); if (lane >= o) sc += x; }
    if (lane == 63) wsum[wv] = sc;
    __syncthreads();
    int wb = 0;
    for (int j = 0; j < wv; ++j) wb += wsum[j];
    int run = s_run;
    if (base + t < NBK) {
      int ex = run + wb + sc - v;
      bbase[base + t] = ex; bcursor[base + t] = ex;
    }
    __syncthreads();
    if (t == 255) s_run = run + wsum[0] + wsum[1] + wsum[2] + wsum[3];
    __syncthreads();
  }
  if (t == 0) { bbase[NBK] = s_run; offs[TOTR] = s_run; }
}

// Pass 3: block-binned scatter into bucket-major ebuf.
// ebuf entry: x = (rowLocal<<19) | (col + coff)  [9+19 bits], y = val bits.
__global__ __launch_bounds__(256) void bscatter_k(Bld b, int* __restrict__ bcursor,
    uint2* __restrict__ ebuf, int totE) {
  __shared__ int cnt[NBK];
  __shared__ int gb[NBK];
  int t = threadIdx.x;
  for (int i = t; i < NBK; i += 256) cnt[i] = 0;
  __syncthreads();
  int g0 = blockIdx.x * EPB;
  int gend = min(g0 + EPB, totE);
  unsigned pk[32];  // (bucket<<22)|(rowLocal<<13)|localPos   10+9+13 bits
  for (int j = 0; j < 32; ++j) {
    int g = g0 + t + j * 256;
    if (g < gend) {
      int l = list_of(b, g);
      int i = g - b.eoff[l];
      int drow = b.base[l] + b.rows[l][i];
      int bk = drow >> 9, rl = drow & 511;
      int lp = atomicAdd(&cnt[bk], 1);
      pk[j] = ((unsigned)bk << 22) | ((unsigned)rl << 13) | (unsigned)lp;
    }
  }
  __syncthreads();
  for (int i = t; i < NBK; i += 256) {
    int c = cnt[i];
    if (c) gb[i] = atomicAdd(&bcursor[i], c);
  }
  __syncthreads();
  for (int j = 0; j < 32; ++j) {
    int g = g0 + t + j * 256;
    if (g >= gend) break;
    unsigned v = pk[j];
    int bk = v >> 22, rl = (v >> 13) & 511, lp = v & 0x1FFF;
    int l = list_of(b, g);
    int i = g - b.eoff[l];
    unsigned cc = (unsigned)(b.cols[l][i] + b.coff[l]);
    ebuf[gb[bk] + lp] = make_uint2(((unsigned)rl << 19) | cc,
                                   __float_as_uint(b.vals[l][i]));
  }
}

// Pass 4: one block per bucket; row counts + scan in LDS -> offs; permute.
__global__ __launch_bounds__(256) void fine_k(const uint2* __restrict__ ebuf,
    const int* __restrict__ bbase, int* __restrict__ offs,
    uint2* __restrict__ edges) {
  __shared__ int rcnt[512];
  __shared__ int rcur[512];
  __shared__ int wsum[4];
  int bk = blockIdx.x, t = threadIdx.x;
  rcnt[t] = 0; rcnt[t + 256] = 0;
  __syncthreads();
  int gbeg = bbase[bk], gend = bbase[bk + 1];
  for (int e = gbeg + t; e < gend; e += 256)
    atomicAdd(&rcnt[ebuf[e].x >> 19], 1);
  __syncthreads();
  int a0 = rcnt[2 * t], a1 = rcnt[2 * t + 1];
  int ts = a0 + a1, sc = ts;
  int lane = t & 63, wv = t >> 6;
#pragma unroll
  for (int o = 1; o < 64; o <<= 1) { int x = __shfl_up(sc, o, 64); if (lane >= o) sc += x; }
  if (lane == 63) wsum[wv] = sc;
  __syncthreads();
  int wb = 0;
  for (int j = 0; j < wv; ++j) wb += wsum[j];
  int ex = wb + sc - ts;
  __syncthreads();  // all rcnt reads complete before overwrite
  rcnt[2 * t] = ex;      rcnt[2 * t + 1] = ex + a0;
  rcur[2 * t] = ex;      rcur[2 * t + 1] = ex + a0;
  __syncthreads();
  int rfirst = bk << 9;
  for (int i = t; i < 512; i += 256) {
    int row = rfirst + i;
    if (row < TOTR) offs[row] = gbeg + rcnt[i];
  }
  for (int e = gbeg + t; e < gend; e += 256) {
    uint2 ev = ebuf[e];
    int rl = ev.x >> 19;
    int lp = atomicAdd(&rcur[rl], 1);
    edges[gbeg + lp] = make_uint2(ev.x & 0x7FFFFu, ev.y);
  }
}

// ------- init: fp32 embs [4][N][64] -> TYPE-MAJOR bf16 buf [4][TOTR][64] -------

__global__ __launch_bounds__(256) void init_k(const float* __restrict__ embs,
    uint2* __restrict__ buf, int nrows, int rowoff) {
  int idx = blockIdx.x * 256 + threadIdx.x;  // one uint2 (4 dims) per thread
  if (idx >= nrows * 64) return;
  int u = idx >> 6, q = idx & 63;
  int k = q >> 4, d4 = q & 15;
  const float4 f = *(const float4*)(embs + ((size_t)k * nrows + u) * 64 + d4 * 4);
  uint2 o;
  o.x = (bfr(f.y) << 16) | bfr(f.x);
  o.y = (bfr(f.w) << 16) | bfr(f.z);
  buf[((size_t)k * TOTR + rowoff + u) * 16 + d4] = o;
}

// ---------------- pull-mode SpMM, 2 types per pass ----------------
// Lanes 0-31 gather type kbase, lanes 32-63 type kbase+1, same edge stream
// (wave-wide shfl broadcasts). Per-pass gather pool = 77 MB -> L3-resident.

__global__ __launch_bounds__(256) void spmm2_k(
    const unsigned* __restrict__ x, unsigned* __restrict__ nxt,
    const int* __restrict__ offs, const uint2* __restrict__ edges, int kbase) {
  int w = (blockIdx.x * 256 + threadIdx.x) >> 6;   // dest row
  int lane = threadIdx.x & 63;
  if (w >= TOTR) return;
  int hl = lane & 31;
  int k = kbase + (lane >> 5);
  const unsigned* xk = x + (size_t)k * ((size_t)TOTR * 32);
  float a0 = 0.f, a1 = 0.f;
  int beg = offs[w], end = offs[w + 1];
  for (int e0 = beg; e0 < end; e0 += 64) {
    int nn = min(64, end - e0);
    uint2 ev = make_uint2(0u, 0u);
    if (lane < nn) ev = edges[e0 + lane];
    int nb = (nn + 15) & ~15;
    for (int s = 0; s < nb; s += 16) {
      unsigned d[16];
#pragma unroll
      for (int j = 0; j < 16; ++j) {
        unsigned c = (unsigned)__shfl((int)ev.x, s + j);
        d[j] = xk[(size_t)c * 32u + (unsigned)hl];
      }
#pragma unroll
      for (int j = 0; j < 16; ++j) {
        float v = __uint_as_float((unsigned)__shfl((int)ev.y, s + j));
        a0 += v * blo(d[j]);
        a1 += v * bhi(d[j]);
      }
    }
  }
  nxt[((size_t)k * TOTR + w) * 32 + hl] = (bfr(a1) << 16) | bfr(a0);
}

// ---------------- final: out = relu(((e0 + l1 + l2)/3) @ W_k) ----------------

__global__ __launch_bounds__(256) void xform_k(float* __restrict__ out,
    const float* __restrict__ uembs, const float* __restrict__ iembs,
    const uint2* __restrict__ b1, const uint2* __restrict__ b0,
    const float* __restrict__ Wu, const float* __restrict__ Wv) {
  const int utiles = NU / 64;  // 3125
  int tile = blockIdx.x;
  const float* embs; const float* W; float* base; int nrows, row0, rowbase;
  if (tile < utiles) {
    embs = uembs; W = Wu; base = out; nrows = NU; row0 = tile * 64; rowbase = 0;
  } else {
    embs = iembs; W = Wv; base = out + (size_t)NU * 256; nrows = NI;
    row0 = (tile - utiles) * 64; rowbase = NU;
  }
  __shared__ float Xs[64][68];
  __shared__ float Ws[64][68];
  int t = threadIdx.x;
  int tr = t >> 4, tc = (t & 15) * 4;
  const float inv3 = 1.f / 3.f;
  for (int k = 0; k < 4; ++k) {
#pragma unroll
    for (int i = 0; i < 4; ++i) {
      int e = t + i * 256;  // 0..1023 float4-slots over the 64x64 tile
      int r = e >> 4, c4 = e & 15;
      float4 wv = ((const float4*)(W + (size_t)k * 4096 + (size_t)r * 64))[c4];
      *(float4*)&Ws[r][c4 * 4] = wv;
      int row = row0 + r;
      float4 xv = make_float4(0.f, 0.f, 0.f, 0.f);
      if (row < nrows) {
        const float4 e0 = *(const float4*)(embs + ((size_t)k * nrows + row) * 64 + c4 * 4);
        uint2 p1 = b1[((size_t)k * TOTR + rowbase + row) * 16 + c4];
        uint2 p2 = b0[((size_t)k * TOTR + rowbase + row) * 16 + c4];
        xv.x = (e0.x + blo(p1.x) + blo(p2.x)) * inv3;
        xv.y = (e0.y + bhi(p1.x) + bhi(p2.x)) * inv3;
        xv.z = (e0.z + blo(p1.y) + blo(p2.y)) * inv3;
        xv.w = (e0.w + bhi(p1.y) + bhi(p2.y)) * inv3;
      }
      *(float4*)&Xs[r][c4 * 4] = xv;
    }
    __syncthreads();
    float y[4][4];
#pragma unroll
    for (int i = 0; i < 4; ++i)
#pragma unroll
      for (int j = 0; j < 4; ++j) y[i][j] = 0.f;
    for (int j = 0; j < 64; ++j) {
      float xr[4], wc[4];
#pragma unroll
      for (int i = 0; i < 4; ++i) { xr[i] = Xs[tr * 4 + i][j]; wc[i] = Ws[j][tc + i]; }
#pragma unroll
      for (int i = 0; i < 4; ++i)
#pragma unroll
        for (int jj = 0; jj < 4; ++jj) y[i][jj] += xr[i] * wc[jj];
    }
#pragma unroll
    for (int i = 0; i < 4; ++i) {
      int row = row0 + tr * 4 + i;
      if (row < nrows) {
        float4 o = make_float4(fmaxf(y[i][0], 0.f), fmaxf(y[i][1], 0.f),
                               fmaxf(y[i][2], 0.f), fmaxf(y[i][3], 0.f));
        ((float4*)(base + (size_t)row * 256 + k * 64))[t & 15] = o;
      }
    }
    __syncthreads();
  }
}

// ---------------- driver ----------------

extern "C" void kernel_launch(void* const* d_in, const int* in_sizes, int n_in,
                              void* d_out, int out_size, void* d_ws, size_t ws_size,
                              hipStream_t stream) {
  Bld b;
  const int rows_idx[6] = {0, 3, 6, 9, 12, 15};
  const int dbase[6] = {0, 0, NU / 2, NU, NU + NI / 2, NU};
  const int coff[6]  = {0, NU, NU, 0, 0, NU};
  int totE = 0;
  for (int l = 0; l < 6; ++l) {
    b.rows[l] = (const int*)d_in[rows_idx[l]];
    b.cols[l] = (const int*)d_in[rows_idx[l] + 1];
    b.vals[l] = (const float*)d_in[rows_idx[l] + 2];
    b.base[l] = dbase[l];
    b.coff[l] = coff[l];
    b.eoff[l] = totE;
    totE += in_sizes[rows_idx[l]];
  }
  b.eoff[6] = totE;

  char* basep = (char*)d_ws; size_t off = 0;
  auto alloc = [&](size_t bytes) -> void* {
    void* r = basep + off; off = (off + bytes + 255) & ~(size_t)255; return r;
  };
  unsigned* bufA = (unsigned*)alloc((size_t)TOTR * 128 * 4);  // [4][TOTR][64 bf16]
  unsigned* bufB = (unsigned*)alloc((size_t)TOTR * 128 * 4);
  int* offs = (int*)alloc((size_t)(TOTR + 1) * 4);
  int* bcount = (int*)alloc((size_t)NBK * 4);
  int* bbase = (int*)alloc((size_t)(NBK + 1) * 4);
  int* bcursor = (int*)alloc((size_t)NBK * 4);
  uint2* edges = (uint2*)alloc((size_t)totE * 8);
  uint2* ebuf = (uint2*)bufB;  // bufB is free during the build phase (67MB < 153MB)

  hipMemsetAsync(bcount, 0, (size_t)NBK * 4, stream);
  int nblk = (totE + EPB - 1) / EPB;
  bhist_k<<<nblk, 256, 0, stream>>>(b, bcount, totE);
  bscan_k<<<1, 256, 0, stream>>>(bcount, bbase, bcursor, offs);
  bscatter_k<<<nblk, 256, 0, stream>>>(b, bcursor, ebuf, totE);
  fine_k<<<NBK, 256, 0, stream>>>(ebuf, bbase, offs, edges);

  const float* user_embs = (const float*)d_in[18];
  const float* item_embs = (const float*)d_in[19];
  const float* W_u = (const float*)d_in[20];
  const float* W_v = (const float*)d_in[21];

  init_k<<<(NU * 64 + 255) / 256, 256, 0, stream>>>(user_embs, (uint2*)bufA, NU, 0);
  init_k<<<(NI * 64 + 255) / 256, 256, 0, stream>>>(item_embs, (uint2*)bufA, NI, NU);

  const int sgrid = TOTR / 4;  // 75000 blocks, 4 waves each = 1 wave/row
  // layer 1: bufA -> bufB (2 type-passes); layer 2: bufB -> bufA
  spmm2_k<<<sgrid, 256, 0, stream>>>(bufA, bufB, offs, edges, 0);
  spmm2_k<<<sgrid, 256, 0, stream>>>(bufA, bufB, offs, edges, 2);
  spmm2_k<<<sgrid, 256, 0, stream>>>(bufB, bufA, offs, edges, 0);
  spmm2_k<<<sgrid, 256, 0, stream>>>(bufB, bufA, offs, edges, 2);

  int tiles = NU / 64 + (NI + 63) / 64;
  xform_k<<<tiles, 256, 0, stream>>>((float*)d_out, user_embs, item_embs,
      (const uint2*)bufB, (const uint2*)bufA, W_u, W_v);
}

// Round 5
// 2151.391 us; speedup vs baseline: 1.0435x; 1.0435x over previous
//
#include <hip/hip_runtime.h>

#define NU 200000
#define NI 100000
#define TOTR (NU + NI)   // merged dest rows: users 0..NU-1, items NU..NU+NI-1
#define NBK 586          // ceil(TOTR/512) row-buckets of 512 rows
#define EPB 8192         // edges per block in build kernels (32/thread)
#define CAP 32768        // fixed ebuf slots per bucket (max bucket ~21.5K + 76 sigma)

// Per-list dest-row bases and source-column offsets (merged row space):
//   l0 u2u     dest r         col +0
//   l1 u2i f0  dest r         col +NU
//   l2 u2i f1  dest r+NU/2    col +NU
//   l3 i2u f0  dest NU+r      col +0
//   l4 i2u f1  dest NU+NI/2+r col +0
//   l5 i2i     dest NU+r      col +NU

struct Bld {
  const int* rows[6]; const int* cols[6]; const float* vals[6];
  int base[6]; int coff[6];
  int eoff[7];  // exclusive prefix of edge counts over the 6 lists
  int* bcursor;
  uint2* ebuf;
};

// ---------------- bf16 helpers ----------------

__device__ __forceinline__ unsigned bfr(float f) {  // fp32 -> bf16 bits, RTNE
  unsigned u = __float_as_uint(f);
  return (u + 0x7FFFu + ((u >> 16) & 1u)) >> 16;
}
__device__ __forceinline__ float blo(unsigned p) { return __uint_as_float(p << 16); }
__device__ __forceinline__ float bhi(unsigned p) { return __uint_as_float(p & 0xFFFF0000u); }

__device__ __forceinline__ int list_of(const Bld& b, int g) {
  int l = 0;
#pragma unroll
  for (int k = 0; k < 5; ++k) l += (g >= b.eoff[k + 1]) ? 1 : 0;
  return l;
}

// ---------------- bucketed CSR build (no pre-histogram) ----------------

// Pass 1: block-binned scatter into fixed-stride bucket-major ebuf.
// LDS per-bucket count (atomic return = local pos), one global atomic per
// bucket per block reserves a contiguous range at bk*CAP + cursor.
// ebuf entry: x = (rowLocal<<19) | (col + coff)  [9+19 bits], y = val bits.
__global__ __launch_bounds__(256) void bscatter_k(Bld b, int totE) {
  __shared__ int cnt[NBK];
  __shared__ int gb[NBK];
  int t = threadIdx.x;
  for (int i = t; i < NBK; i += 256) cnt[i] = 0;
  __syncthreads();
  int g0 = blockIdx.x * EPB;
  int gend = min(g0 + EPB, totE);
  unsigned pk[32];  // (bucket<<22)|(rowLocal<<13)|localPos   10+9+13 bits
  for (int j = 0; j < 32; ++j) {
    int g = g0 + t + j * 256;
    if (g < gend) {
      int l = list_of(b, g);
      int i = g - b.eoff[l];
      int drow = b.base[l] + b.rows[l][i];
      int bk = drow >> 9, rl = drow & 511;
      int lp = atomicAdd(&cnt[bk], 1);
      pk[j] = ((unsigned)bk << 22) | ((unsigned)rl << 13) | (unsigned)lp;
    }
  }
  __syncthreads();
  for (int i = t; i < NBK; i += 256) {
    int c = cnt[i];
    if (c) gb[i] = atomicAdd(&b.bcursor[i], c);
  }
  __syncthreads();
  for (int j = 0; j < 32; ++j) {
    int g = g0 + t + j * 256;
    if (g >= gend) break;
    unsigned v = pk[j];
    int bk = v >> 22, rl = (v >> 13) & 0x1FF, lp = v & 0x1FFF;
    int l = list_of(b, g);
    int i = g - b.eoff[l];
    unsigned cc = (unsigned)(b.cols[l][i] + b.coff[l]);
    b.ebuf[(size_t)bk * CAP + gb[bk] + lp] =
        make_uint2(((unsigned)rl << 19) | cc, __float_as_uint(b.vals[l][i]));
  }
}

// Pass 2: exclusive scan of 586 bucket counts -> bbase; offs[TOTR] = total
__global__ __launch_bounds__(256) void bscan_k(const int* __restrict__ bcount,
    int* __restrict__ bbase, int* __restrict__ offs) {
  __shared__ int s_run;
  __shared__ int wsum[4];
  int t = threadIdx.x, lane = t & 63, wv = t >> 6;
  if (t == 0) s_run = 0;
  __syncthreads();
  for (int base = 0; base < NBK; base += 256) {
    int v = (base + t < NBK) ? bcount[base + t] : 0;
    int sc = v;
#pragma unroll
    for (int o = 1; o < 64; o <<= 1) { int x = __shfl_up(sc, o, 64); if (lane >= o) sc += x; }
    if (lane == 63) wsum[wv] = sc;
    __syncthreads();
    int wb = 0;
    for (int j = 0; j < wv; ++j) wb += wsum[j];
    int run = s_run;
    if (base + t < NBK) bbase[base + t] = run + wb + sc - v;
    __syncthreads();
    if (t == 255) s_run = run + wsum[0] + wsum[1] + wsum[2] + wsum[3];
    __syncthreads();
  }
  if (t == 0) { bbase[NBK] = s_run; offs[TOTR] = s_run; }
}

// Pass 3: one block per bucket; row counts + scan in LDS -> offs; permute
// fixed-stride ebuf slice into contiguous row-sorted edges.
__global__ __launch_bounds__(256) void fine_k(const uint2* __restrict__ ebuf,
    const int* __restrict__ bcnt, const int* __restrict__ bbase,
    int* __restrict__ offs, uint2* __restrict__ edges) {
  __shared__ int rcnt[512];
  __shared__ int rcur[512];
  __shared__ int wsum[4];
  int bk = blockIdx.x, t = threadIdx.x;
  rcnt[t] = 0; rcnt[t + 256] = 0;
  __syncthreads();
  int cnt = bcnt[bk];
  size_t ib = (size_t)bk * CAP;
  int ob = bbase[bk];
  for (int e = t; e < cnt; e += 256)
    atomicAdd(&rcnt[ebuf[ib + e].x >> 19], 1);
  __syncthreads();
  int a0 = rcnt[2 * t], a1 = rcnt[2 * t + 1];
  int ts = a0 + a1, sc = ts;
  int lane = t & 63, wv = t >> 6;
#pragma unroll
  for (int o = 1; o < 64; o <<= 1) { int x = __shfl_up(sc, o, 64); if (lane >= o) sc += x; }
  if (lane == 63) wsum[wv] = sc;
  __syncthreads();
  int wb = 0;
  for (int j = 0; j < wv; ++j) wb += wsum[j];
  int ex = wb + sc - ts;
  __syncthreads();  // all rcnt reads complete before overwrite
  rcnt[2 * t] = ex;      rcnt[2 * t + 1] = ex + a0;
  rcur[2 * t] = ex;      rcur[2 * t + 1] = ex + a0;
  __syncthreads();
  int rfirst = bk << 9;
  for (int i = t; i < 512; i += 256) {
    int row = rfirst + i;
    if (row < TOTR) offs[row] = ob + rcnt[i];
  }
  for (int e = t; e < cnt; e += 256) {
    uint2 ev = ebuf[ib + e];
    int rl = ev.x >> 19;
    int lp = atomicAdd(&rcur[rl], 1);
    edges[ob + lp] = make_uint2(ev.x & 0x7FFFFu, ev.y);
  }
}

// ---------------- init: fp32 embs [4][N][64] -> bf16 buf [N][256] ----------------

__global__ __launch_bounds__(256) void init_k(const float* __restrict__ embs,
                                              uint2* __restrict__ buf, int nrows) {
  int idx = blockIdx.x * 256 + threadIdx.x;  // one uint2 (4 elems) per thread
  if (idx >= nrows * 64) return;
  int u = idx >> 6, q = idx & 63;
  int k = q >> 4, d = (q & 15) * 4;
  const float4 f = *(const float4*)(embs + ((size_t)k * nrows + u) * 64 + d);
  uint2 o;
  o.x = (bfr(f.y) << 16) | bfr(f.x);
  o.y = (bfr(f.w) << 16) | bfr(f.z);
  buf[idx] = o;
}

// ---------------- pull-mode SpMM over bf16 rows ----------------
// Batch-16 gathers, zero-padded: lanes >= nn hold (col=0, val=0); padded
// gathers all hit row 0 (one hot line) and val=0 makes the FMA a no-op.

__device__ __forceinline__ void gacc(float a[4], const uint2* __restrict__ x,
    int beg, int end, const uint2* __restrict__ edges, int lane) {
  for (int e0 = beg; e0 < end; e0 += 64) {
    int nn = min(64, end - e0);
    uint2 ev = make_uint2(0u, 0u);
    if (lane < nn) ev = edges[e0 + lane];
    int nb = (nn + 15) & ~15;
    for (int s = 0; s < nb; s += 16) {
      uint2 d[16];
#pragma unroll
      for (int j = 0; j < 16; ++j) {
        unsigned c = (unsigned)__shfl((int)ev.x, s + j);
        d[j] = x[(size_t)c * 64u + (unsigned)lane];
      }
#pragma unroll
      for (int j = 0; j < 16; ++j) {
        float v = __uint_as_float((unsigned)__shfl((int)ev.y, s + j));
        a[0] += v * blo(d[j].x);
        a[1] += v * bhi(d[j].x);
        a[2] += v * blo(d[j].y);
        a[3] += v * bhi(d[j].y);
      }
    }
  }
}

__global__ __launch_bounds__(256) void spmm_k(
    const uint2* __restrict__ x, uint2* __restrict__ nxt,
    const int* __restrict__ offs, const uint2* __restrict__ edges, int nrows) {
  int w = (blockIdx.x * 256 + threadIdx.x) >> 6;
  int lane = threadIdx.x & 63;
  if (w >= nrows) return;
  float a[4] = {0.f, 0.f, 0.f, 0.f};
  gacc(a, x, offs[w], offs[w + 1], edges, lane);
  uint2 o;
  o.x = (bfr(a[1]) << 16) | bfr(a[0]);
  o.y = (bfr(a[3]) << 16) | bfr(a[2]);
  nxt[(size_t)w * 64 + lane] = o;
}

// ---------------- final: out = relu(((e0 + l1 + l2)/3) @ W_k) ----------------

__global__ __launch_bounds__(256) void xform_k(float* __restrict__ out,
    const float* __restrict__ uembs, const float* __restrict__ iembs,
    const uint2* __restrict__ u1, const uint2* __restrict__ u0,
    const uint2* __restrict__ i1, const uint2* __restrict__ i0,
    const float* __restrict__ Wu, const float* __restrict__ Wv) {
  const int utiles = NU / 64;  // 3125
  int tile = blockIdx.x;
  const float* embs; const uint2 *b1, *b0; const float* W; float* base; int nrows, row0;
  if (tile < utiles) {
    embs = uembs; b1 = u1; b0 = u0; W = Wu; base = out; nrows = NU; row0 = tile * 64;
  } else {
    embs = iembs; b1 = i1; b0 = i0; W = Wv; base = out + (size_t)NU * 256; nrows = NI;
    row0 = (tile - utiles) * 64;
  }
  __shared__ float Xs[64][68];
  __shared__ float Ws[64][68];
  int t = threadIdx.x;
  int tr = t >> 4, tc = (t & 15) * 4;
  const float inv3 = 1.f / 3.f;
  for (int k = 0; k < 4; ++k) {
#pragma unroll
    for (int i = 0; i < 4; ++i) {
      int e = t + i * 256;  // 0..1023 float4-slots over the 64x64 tile
      int r = e >> 4, c4 = e & 15;
      float4 wv = ((const float4*)(W + (size_t)k * 4096 + (size_t)r * 64))[c4];
      *(float4*)&Ws[r][c4 * 4] = wv;
      int row = row0 + r;
      float4 xv = make_float4(0.f, 0.f, 0.f, 0.f);
      if (row < nrows) {
        const float4 e0 = *(const float4*)(embs + ((size_t)k * nrows + row) * 64 + c4 * 4);
        uint2 p1 = b1[(size_t)row * 64 + k * 16 + c4];
        uint2 p2 = b0[(size_t)row * 64 + k * 16 + c4];
        xv.x = (e0.x + blo(p1.x) + blo(p2.x)) * inv3;
        xv.y = (e0.y + bhi(p1.x) + bhi(p2.x)) * inv3;
        xv.z = (e0.z + blo(p1.y) + blo(p2.y)) * inv3;
        xv.w = (e0.w + bhi(p1.y) + bhi(p2.y)) * inv3;
      }
      *(float4*)&Xs[r][c4 * 4] = xv;
    }
    __syncthreads();
    float y[4][4];
#pragma unroll
    for (int i = 0; i < 4; ++i)
#pragma unroll
      for (int j = 0; j < 4; ++j) y[i][j] = 0.f;
    for (int j = 0; j < 64; ++j) {
      float xr[4], wc[4];
#pragma unroll
      for (int i = 0; i < 4; ++i) { xr[i] = Xs[tr * 4 + i][j]; wc[i] = Ws[j][tc + i]; }
#pragma unroll
      for (int i = 0; i < 4; ++i)
#pragma unroll
        for (int jj = 0; jj < 4; ++jj) y[i][jj] += xr[i] * wc[jj];
    }
#pragma unroll
    for (int i = 0; i < 4; ++i) {
      int row = row0 + tr * 4 + i;
      if (row < nrows) {
        float4 o = make_float4(fmaxf(y[i][0], 0.f), fmaxf(y[i][1], 0.f),
                               fmaxf(y[i][2], 0.f), fmaxf(y[i][3], 0.f));
        ((float4*)(base + (size_t)row * 256 + k * 64))[t & 15] = o;
      }
    }
    __syncthreads();
  }
}

// ---------------- driver ----------------

extern "C" void kernel_launch(void* const* d_in, const int* in_sizes, int n_in,
                              void* d_out, int out_size, void* d_ws, size_t ws_size,
                              hipStream_t stream) {
  Bld b;
  const int rows_idx[6] = {0, 3, 6, 9, 12, 15};
  const int dbase[6] = {0, 0, NU / 2, NU, NU + NI / 2, NU};
  const int coff[6]  = {0, NU, NU, 0, 0, NU};
  int totE = 0;
  for (int l = 0; l < 6; ++l) {
    b.rows[l] = (const int*)d_in[rows_idx[l]];
    b.cols[l] = (const int*)d_in[rows_idx[l] + 1];
    b.vals[l] = (const float*)d_in[rows_idx[l] + 2];
    b.base[l] = dbase[l];
    b.coff[l] = coff[l];
    b.eoff[l] = totE;
    totE += in_sizes[rows_idx[l]];
  }
  b.eoff[6] = totE;

  char* basep = (char*)d_ws; size_t off = 0;
  auto alloc = [&](size_t bytes) -> void* {
    void* r = basep + off; off = (off + bytes + 255) & ~(size_t)255; return r;
  };
  size_t embBytes = (size_t)TOTR * 64 * 8;       // 153.6 MB  [TOTR][64 uint2]
  size_t ebufBytes = (size_t)NBK * CAP * 8;      // 153.62 MB fixed-stride buckets
  uint2* bufA = (uint2*)alloc(embBytes);
  uint2* bufB = (uint2*)alloc(ebufBytes > embBytes ? ebufBytes : embBytes);
  int* offs = (int*)alloc((size_t)(TOTR + 1) * 4);
  int* bcursor = (int*)alloc((size_t)NBK * 4);
  int* bbase = (int*)alloc((size_t)(NBK + 1) * 4);
  uint2* edges = (uint2*)alloc((size_t)totE * 8);
  b.bcursor = bcursor;
  b.ebuf = bufB;  // bufB is free during the build phase

  hipMemsetAsync(bcursor, 0, (size_t)NBK * 4, stream);
  int nblk = (totE + EPB - 1) / EPB;
  bscatter_k<<<nblk, 256, 0, stream>>>(b, totE);
  bscan_k<<<1, 256, 0, stream>>>(bcursor, bbase, offs);
  fine_k<<<NBK, 256, 0, stream>>>(b.ebuf, bcursor, bbase, offs, edges);

  const float* user_embs = (const float*)d_in[18];
  const float* item_embs = (const float*)d_in[19];
  const float* W_u = (const float*)d_in[20];
  const float* W_v = (const float*)d_in[21];

  init_k<<<(NU * 64 + 255) / 256, 256, 0, stream>>>(user_embs, bufA, NU);
  init_k<<<(NI * 64 + 255) / 256, 256, 0, stream>>>(item_embs, bufA + (size_t)NU * 64, NI);

  // layer 1: bufA -> bufB (overwrites consumed ebuf); layer 2: bufB -> bufA
  spmm_k<<<(TOTR + 3) / 4, 256, 0, stream>>>(bufA, bufB, offs, edges, TOTR);
  spmm_k<<<(TOTR + 3) / 4, 256, 0, stream>>>(bufB, bufA, offs, edges, TOTR);

  int tiles = NU / 64 + (NI + 63) / 64;
  xform_k<<<tiles, 256, 0, stream>>>((float*)d_out, user_embs, item_embs,
      bufB, bufA, bufB + (size_t)NU * 64, bufA + (size_t)NU * 64, W_u, W_v);
}